// Round 2
// baseline (2553.624 us; speedup 1.0000x reference)
//
#include <hip/hip_runtime.h>
#include <math.h>

#define HW_ 65536
#define NB 2

__device__ __forceinline__ float wave_reduce_sum(float v) {
    #pragma unroll
    for (int off = 32; off; off >>= 1) v += __shfl_down(v, off, 64);
    return v;
}

// ---------------------------------------------------------------------------
// Weight transpose: wT[c*OC + o] = w[o*IC + c], all 9 matrices concatenated.
// ---------------------------------------------------------------------------
__global__ __launch_bounds__(256) void transpose_w_k(
    const float* __restrict__ q1w, const float* __restrict__ q2w,
    const float* __restrict__ m1w, const float* __restrict__ m2w,
    const float* __restrict__ pEw, const float* __restrict__ p1w,
    const float* __restrict__ p2w, const float* __restrict__ o1w,
    const float* __restrict__ o2w, float* __restrict__ wt)
{
    const int idx = blockIdx.x * 256 + threadIdx.x;
    if (idx >= 110592) return;
    const int base[10] = {0,6912,13824,16128,18432,55296,64512,73728,92160,110592};
    const int OCs[9] = {144,144,48,48,384,192,192,96,96};
    const int ICs[9] = {48,48,48,48,96,48,48,192,192};
    int s = 0;
    #pragma unroll
    for (int i = 1; i < 9; i++) if (idx >= base[i]) s = i;
    const int local = idx - base[s];
    const int OC = OCs[s], IC = ICs[s];
    const int c = local / OC, o = local - c * OC;
    const float* srcs[9] = {q1w,q2w,m1w,m2w,pEw,p1w,p2w,o1w,o2w};
    wt[idx] = srcs[s][o * IC + c];
}

// ---------------------------------------------------------------------------
// 1x1 conv with scalar (wave-uniform) weight loads from transposed weights.
// wT[c*wStride + wOff + oc0 + o]. One thread = one spatial position, OC accums.
// MODE 0: out = acc; MODE 1: out += acc; MODE 3: out += res + acc.
// ---------------------------------------------------------------------------
template <int OC, int CIN, int MODE>
__global__ __launch_bounds__(256) void conv1x1s_k(
    const float* __restrict__ in, long inBS,
    const float* __restrict__ wT, int wStride, int wOff,
    const float* __restrict__ res,
    float* __restrict__ out, long outBS, int ocOut)
{
    const int tid = threadIdx.x;
    const long p = (long)blockIdx.x * 256 + tid;
    const int b = blockIdx.y;
    const int oc0 = blockIdx.z * OC;
    const float* inp = in + (long)b * inBS + p;

    float acc[OC];
    #pragma unroll
    for (int o = 0; o < OC; o++) acc[o] = 0.f;

    #pragma unroll 1
    for (int c = 0; c < CIN; c += 4) {
        const float x0 = inp[(long)(c + 0) * HW_];
        const float x1 = inp[(long)(c + 1) * HW_];
        const float x2 = inp[(long)(c + 2) * HW_];
        const float x3 = inp[(long)(c + 3) * HW_];
        const float* w0 = wT + (long)(c + 0) * wStride + wOff + oc0;
        const float* w1 = w0 + wStride;
        const float* w2 = w1 + wStride;
        const float* w3 = w2 + wStride;
        #pragma unroll
        for (int o = 0; o < OC; o++)
            acc[o] = fmaf(w0[o], x0, fmaf(w1[o], x1, fmaf(w2[o], x2, fmaf(w3[o], x3, acc[o]))));
    }

    float* op = out + (long)b * outBS + (long)(ocOut + oc0) * HW_ + p;
    if (MODE == 0) {
        #pragma unroll
        for (int o = 0; o < OC; o++) op[(long)o * HW_] = acc[o];
    } else if (MODE == 1) {
        #pragma unroll
        for (int o = 0; o < OC; o++) op[(long)o * HW_] += acc[o];
    } else {
        const float* rp = res + (long)b * outBS + (long)(ocOut + oc0) * HW_ + p;
        #pragma unroll
        for (int o = 0; o < OC; o++) op[(long)o * HW_] += rp[(long)o * HW_] + acc[o];
    }
}

// ---------------------------------------------------------------------------
// depthwise 3x3, pad=1. GATED: out = gelu(gate[p]) * acc (gate == out is safe).
// ---------------------------------------------------------------------------
template <int GATED>
__global__ __launch_bounds__(256) void dw3x3_k(
    const float* __restrict__ in, float* __restrict__ out,
    const float* __restrict__ w, int wOff, int C,
    const float* __restrict__ gate)
{
    const long p = (long)blockIdx.x * 256 + threadIdx.x;
    const int c = blockIdx.y, b = blockIdx.z;
    const long base = ((long)b * C + c) * HW_;
    const int y = (int)(p >> 8), x = (int)(p & 255);
    const float* wp = w + (long)(wOff + c) * 9;
    const float* ip = in + base;
    float acc = 0.f;
    #pragma unroll
    for (int dy = -1; dy <= 1; dy++) {
        int yy = y + dy;
        if ((unsigned)yy >= 256u) continue;
        #pragma unroll
        for (int dx = -1; dx <= 1; dx++) {
            int xx = x + dx;
            if ((unsigned)xx >= 256u) continue;
            acc = fmaf(wp[(dy + 1) * 3 + (dx + 1)], ip[yy * 256 + xx], acc);
        }
    }
    if (GATED) {
        float g = gate[base + p];
        float gg = 0.5f * g * (1.f + erff(g * 0.70710678118654752440f));
        out[base + p] = gg * acc;
    } else {
        out[base + p] = acc;
    }
}

// ---------------------------------------------------------------------------
// Attention stage A: per (chunk, b*8+h, a), partial q·k dots + q/k sq-norms.
// a=0: q from Q2, k from Q1 (attn1); a=1: q from Q1, k from Q2 (attn2).
// part[((a*16+bh)*32 + chunk)*48 + {dot[36], nq[6], nk[6]}]
// ---------------------------------------------------------------------------
__global__ __launch_bounds__(256) void attnA_k(
    const float* __restrict__ Q1, const float* __restrict__ Q2,
    float* __restrict__ part)
{
    const int tid = threadIdx.x;
    const int chunk = blockIdx.x, bh = blockIdx.y, a = blockIdx.z;
    const int b = bh >> 3, h = bh & 7;
    const float* Qq = a ? Q1 : Q2;
    const float* Qk = a ? Q2 : Q1;
    const float* qp = Qq + ((long)b * 144 + h * 6) * HW_;
    const float* kp = Qk + ((long)b * 144 + 48 + h * 6) * HW_;
    const long p0 = (long)chunk * 2048 + tid;

    float dot[36], nq[6], nk[6];
    #pragma unroll
    for (int i = 0; i < 36; i++) dot[i] = 0.f;
    #pragma unroll
    for (int i = 0; i < 6; i++) { nq[i] = 0.f; nk[i] = 0.f; }

    #pragma unroll 1
    for (int r = 0; r < 8; r++) {
        const long p = p0 + r * 256;
        float q[6], k[6];
        #pragma unroll
        for (int c = 0; c < 6; c++) q[c] = qp[(long)c * HW_ + p];
        #pragma unroll
        for (int d = 0; d < 6; d++) k[d] = kp[(long)d * HW_ + p];
        #pragma unroll
        for (int c = 0; c < 6; c++) nq[c] = fmaf(q[c], q[c], nq[c]);
        #pragma unroll
        for (int d = 0; d < 6; d++) nk[d] = fmaf(k[d], k[d], nk[d]);
        #pragma unroll
        for (int c = 0; c < 6; c++)
            #pragma unroll
            for (int d = 0; d < 6; d++) dot[c * 6 + d] = fmaf(q[c], k[d], dot[c * 6 + d]);
    }

    __shared__ float red[4][48];
    const int lane = tid & 63, wid = tid >> 6;
    #pragma unroll
    for (int i = 0; i < 48; i++) {
        float v = (i < 36) ? dot[i] : (i < 42 ? nq[i - 36] : nk[i - 42]);
        v = wave_reduce_sum(v);
        if (!lane) red[wid][i] = v;
    }
    __syncthreads();
    if (tid < 48)
        part[((long)(a * 16 + bh) * 32 + chunk) * 48 + tid]
            = red[0][tid] + red[1][tid] + red[2][tid] + red[3][tid];
}

// ---------------------------------------------------------------------------
// Stage B: reduce partials, normalize, temperature, softmax -> ATT.
// grid 32 = (a*16 + bh), block 64.
// ---------------------------------------------------------------------------
__global__ void attnB_k(const float* __restrict__ part,
                        const float* __restrict__ t1, const float* __restrict__ t2,
                        float* __restrict__ att)
{
    const int abh = blockIdx.x, tid = threadIdx.x;
    const int a = abh >> 4, bh = abh & 15, b = bh >> 3, h = bh & 7;
    __shared__ float s[48];
    if (tid < 48) {
        float v = 0.f;
        for (int ch = 0; ch < 32; ch++) v += part[((long)abh * 32 + ch) * 48 + tid];
        s[tid] = v;
    }
    __syncthreads();
    if (tid < 6) {
        const int c = tid;
        const float tv = a ? t2[h] : t1[h];
        const float qn = fmaxf(sqrtf(s[36 + c]), 1e-12f);
        float raw[6];
        #pragma unroll
        for (int d = 0; d < 6; d++)
            raw[d] = tv * s[c * 6 + d] / (qn * fmaxf(sqrtf(s[42 + d]), 1e-12f));
        float m = raw[0];
        #pragma unroll
        for (int d = 1; d < 6; d++) m = fmaxf(m, raw[d]);
        float e[6], sum = 0.f;
        #pragma unroll
        for (int d = 0; d < 6; d++) { e[d] = expf(raw[d] - m); sum += e[d]; }
        const float inv = 1.f / sum;
        #pragma unroll
        for (int d = 0; d < 6; d++)
            att[((size_t)(a * 2 + b) * 8 + h) * 36 + c * 6 + d] = e[d] * inv;
    }
}

// ---------------------------------------------------------------------------
// Fused: O = softmax(att) @ V ; dout[ocOut..ocOut+47] = x + mid @ O.
// att is pre-offset by branch (a*576); att reads are wave-uniform (s_load).
// ---------------------------------------------------------------------------
__global__ __launch_bounds__(256) void attn_mid_k(
    const float* __restrict__ Qv, const float* __restrict__ att,
    const float* __restrict__ x, const float* __restrict__ midT,
    float* __restrict__ dout, int ocOut)
{
    const int tid = threadIdx.x;
    const long p = (long)blockIdx.x * 256 + tid;
    const int b = blockIdx.y;
    const float* vp = Qv + ((long)b * 144 + 96) * HW_ + p;
    const float* ap = att + (long)b * 288;
    const float* xp = x + (long)b * (48L * HW_) + p;

    float acc[48];
    #pragma unroll
    for (int o = 0; o < 48; o++) acc[o] = xp[(long)o * HW_];

    #pragma unroll 1
    for (int h = 0; h < 8; h++) {
        float v[6];
        #pragma unroll
        for (int d = 0; d < 6; d++) v[d] = vp[(long)(h * 6 + d) * HW_];
        #pragma unroll 1
        for (int c = 0; c < 6; c++) {
            float s = 0.f;
            #pragma unroll
            for (int d = 0; d < 6; d++) s = fmaf(ap[h * 36 + c * 6 + d], v[d], s);
            const float* wc = midT + (h * 6 + c) * 48;
            #pragma unroll
            for (int o = 0; o < 48; o++) acc[o] = fmaf(wc[o], s, acc[o]);
        }
    }
    float* op = dout + ((long)b * 96 + ocOut) * HW_ + p;
    #pragma unroll
    for (int o = 0; o < 48; o++) op[(long)o * HW_] = acc[o];
}

extern "C" void kernel_launch(void* const* d_in, const int* in_sizes, int n_in,
                              void* d_out, int out_size, void* d_ws, size_t ws_size,
                              hipStream_t stream) {
    const float* x1      = (const float*)d_in[0];
    const float* x2      = (const float*)d_in[1];
    const float* t1      = (const float*)d_in[2];
    const float* t2      = (const float*)d_in[3];
    const float* qkv1_w  = (const float*)d_in[4];
    const float* qkv1_dw = (const float*)d_in[5];
    const float* qkv2_w  = (const float*)d_in[6];
    const float* qkv2_dw = (const float*)d_in[7];
    const float* mid1_w  = (const float*)d_in[8];
    const float* mid2_w  = (const float*)d_in[9];
    const float* pE_w    = (const float*)d_in[10];
    const float* pE_dw   = (const float*)d_in[11];
    const float* pE1_w   = (const float*)d_in[12];
    const float* pE1_dw  = (const float*)d_in[13];
    const float* pE2_w   = (const float*)d_in[14];
    const float* pE2_dw  = (const float*)d_in[15];
    const float* po1_w   = (const float*)d_in[16];
    const float* po2_w   = (const float*)d_in[17];
    float* dout = (float*)d_out;
    float* ws = (float*)d_ws;

    const long SZ144 = (long)NB * 144 * HW_;
    const long SZ96  = (long)NB * 96 * HW_;
    const long BS48  = 48L * HW_, BS96 = 96L * HW_, BS144 = 144L * HW_;

    float* T0 = ws;              // phase-1 conv out (144ch)
    float* Q1 = ws + SZ144;
    float* Q2 = ws + 2 * SZ144;
    float* Ba = ws;              // phase-5 buffers
    float* Bb = ws + SZ96;
    float* Bc = ws + 2 * SZ96;
    float* ACC = ws + 3 * SZ96;
    float* TAIL = ws + 3 * SZ144;
    float* ATT  = TAIL;          // 1152
    float* PART = TAIL + 1152;   // 49152
    float* WT   = TAIL + 1152 + 49152;
    float* WTq1 = WT + 0;
    float* WTq2 = WT + 6912;
    float* WTm1 = WT + 13824;
    float* WTm2 = WT + 16128;
    float* WTpE = WT + 18432;
    float* WTp1 = WT + 55296;
    float* WTp2 = WT + 64512;
    float* WTo1 = WT + 73728;
    float* WTo2 = WT + 92160;

    const dim3 blk(256);

    transpose_w_k<<<dim3(432), blk, 0, stream>>>(
        qkv1_w, qkv2_w, mid1_w, mid2_w, pE_w, pE1_w, pE2_w, po1_w, po2_w, WT);

    // --- phase 1: qkv = dw3x3(conv1x1(x)) for both branches
    conv1x1s_k<72,48,0><<<dim3(256, NB, 2), blk, 0, stream>>>(x1, BS48, WTq1, 144, 0, nullptr, T0, BS144, 0);
    dw3x3_k<0><<<dim3(256, 144, NB), blk, 0, stream>>>(T0, Q1, qkv1_dw, 0, 144, nullptr);
    conv1x1s_k<72,48,0><<<dim3(256, NB, 2), blk, 0, stream>>>(x2, BS48, WTq2, 144, 0, nullptr, T0, BS144, 0);
    dw3x3_k<0><<<dim3(256, 144, NB), blk, 0, stream>>>(T0, Q2, qkv2_dw, 0, 144, nullptr);

    // --- phase 2: fused norms+dots (2-stage), softmax
    attnA_k<<<dim3(32, 16, 2), blk, 0, stream>>>(Q1, Q2, PART);
    attnB_k<<<dim3(32), dim3(64), 0, stream>>>(PART, t1, t2, ATT);

    // --- phase 3+4: fused attn-out + mid conv + residual
    attn_mid_k<<<dim3(256, NB), blk, 0, stream>>>(Q1, ATT, x1, WTm1, dout, 0);
    attn_mid_k<<<dim3(256, NB), blk, 0, stream>>>(Q2, ATT + 576, x2, WTm2, dout, 48);

    // --- phase 5: gated FFN tail, 4 chunks of 96 channels
    for (int i = 0; i < 4; i++) {
        conv1x1s_k<96,96,0><<<dim3(256, NB, 1), blk, 0, stream>>>(
            dout, BS96, WTpE, 384, i * 96, nullptr, Ba, BS96, 0);
        dw3x3_k<0><<<dim3(256, 96, NB), blk, 0, stream>>>(Ba, Bb, pE_dw, i * 96, 96, nullptr);
        const float* wp12 = (i < 2 ? WTp1 : WTp2);
        conv1x1s_k<96,48,0><<<dim3(256, NB, 1), blk, 0, stream>>>(
            dout + (i < 2 ? 0 : BS48), BS96, wp12, 192, (i & 1) * 96, nullptr, Bc, BS96, 0);
        const float* dwp = (i < 2 ? pE1_dw : pE2_dw);
        dw3x3_k<1><<<dim3(256, 96, NB), blk, 0, stream>>>(Bc, Bb, dwp, (i & 1) * 96, 96, Bb);
        const float* wpo = (i < 2 ? WTo1 : WTo2) + (size_t)(i & 1) * 96 * 96;
        if (i == 0) {
            conv1x1s_k<96,96,0><<<dim3(256, NB, 1), blk, 0, stream>>>(
                Bb, BS96, wpo, 96, 0, nullptr, ACC, BS96, 0);
        } else if (i < 3) {
            conv1x1s_k<96,96,1><<<dim3(256, NB, 1), blk, 0, stream>>>(
                Bb, BS96, wpo, 96, 0, nullptr, ACC, BS96, 0);
        } else {
            conv1x1s_k<96,96,3><<<dim3(256, NB, 1), blk, 0, stream>>>(
                Bb, BS96, wpo, 96, 0, ACC, dout, BS96, 0);
        }
    }
}

// Round 3
// 768.516 us; speedup vs baseline: 3.3228x; 3.3228x over previous
//
#include <hip/hip_runtime.h>
#include <math.h>

#define HW_ 65536
#define NPX 131072   // 2 batches * 65536 px

typedef __attribute__((ext_vector_type(8))) short b16x8;
typedef __attribute__((ext_vector_type(4))) short b16x4;
typedef __attribute__((ext_vector_type(4))) float f32x4;

__device__ __forceinline__ unsigned short f2b(float f) {
    union { float f; unsigned u; } v; v.f = f;
    unsigned r = v.u + 0x7fffu + ((v.u >> 16) & 1u);
    return (unsigned short)(r >> 16);
}
__device__ __forceinline__ float b2f(unsigned short h) {
    union { unsigned u; float f; } v; v.u = ((unsigned)h) << 16; return v.f;
}

__device__ __forceinline__ float wave_reduce_sum(float v) {
    #pragma unroll
    for (int off = 32; off; off >>= 1) v += __shfl_down(v, off, 64);
    return v;
}

// ---------------------------------------------------------------------------
// Weight prep: fp32 [OC][IC] -> bf16 row-major [OC][Kpad], zero-padded cols.
// Segments (element offsets): qkv1@0[144x64], qkv2@9216, mid1@18432[48x64],
// mid2@21504, pE@24576[384x128], pE1@73728[192x64], pE2@86016, po1@98304
// [96x192], po2@116736. Total 135168.
// pE col map: k<48 -> k ; 64<=k<112 -> k-16 ; else zero (matches D16p pads).
// ---------------------------------------------------------------------------
__global__ __launch_bounds__(256) void wprep_k(
    const float* __restrict__ q1w, const float* __restrict__ q2w,
    const float* __restrict__ m1w, const float* __restrict__ m2w,
    const float* __restrict__ pEw, const float* __restrict__ p1w,
    const float* __restrict__ p2w, const float* __restrict__ o1w,
    const float* __restrict__ o2w, unsigned short* __restrict__ wt)
{
    const int idx = blockIdx.x * 256 + threadIdx.x;
    if (idx >= 135168) return;
    const int base[10] = {0,9216,18432,21504,24576,73728,86016,98304,116736,135168};
    const int KP[9] = {64,64,64,64,128,64,64,192,192};
    const int IC[9] = {48,48,48,48,96,48,48,192,192};
    const float* srcs[9] = {q1w,q2w,m1w,m2w,pEw,p1w,p2w,o1w,o2w};
    int s = 0;
    #pragma unroll
    for (int i = 1; i < 9; i++) if (idx >= base[i]) s = i;
    const int local = idx - base[s];
    const int kp = KP[s], ic = IC[s];
    const int m = local / kp, k = local - m * kp;
    float v = 0.f;
    if (s == 4) {
        if (k < 48) v = srcs[s][m * ic + k];
        else if (k >= 64 && k < 112) v = srcs[s][m * ic + k - 16];
    } else {
        if (k < ic) v = srcs[s][m * ic + k];
    }
    wt[idx] = f2b(v);
}

// ---------------------------------------------------------------------------
// MFMA GEMM: D[m, px] = W[m, k] * X[k, px].
// Block = 4 waves; wave covers BM x 64px (4 n-frags of 16). No LDS.
// A-frag: lane&15 = m, k = kc*32 + (lane>>4)*8 + j  (contig in W row)
// B-frag: lane&15 = n(px), same k mapping (contig in NHWC row)
// D-frag: col = lane&15 (px), row = m*16 + (lane>>4)*4 + j
// BSRC 0: bf16 NHWC [px][Brow], col offset Boff.  BSRC 1: fp32 NCHW, Cin ch.
// EPI 0: bf16 NHWC store [px][Crow]+Coff.
// EPI 1: d_out = b2f(res[px*128 + colmap(row)]) + acc  (fp32 NCHW)
// EPI 2: d_out += acc
// ---------------------------------------------------------------------------
template<int BM, int KC, int BSRC, int EPI>
__global__ __launch_bounds__(256) void gemm_k(
    const unsigned short* __restrict__ B16, int Brow, int Boff,
    const float* __restrict__ Bf32, int Cin,
    const unsigned short* __restrict__ W16,
    unsigned short* __restrict__ out16, int Crow, int Coff,
    float* __restrict__ outf, const unsigned short* __restrict__ res)
{
    constexpr int MF = BM / 16;
    const int tid = threadIdx.x;
    const int lane = tid & 63, w = tid >> 6;
    const int lm = lane & 15, lk = lane >> 4;
    const int m0 = blockIdx.y * BM;
    const long wavepx = (long)blockIdx.x * 256 + w * 64;

    f32x4 acc[4][MF];
    #pragma unroll
    for (int nt = 0; nt < 4; nt++)
        #pragma unroll
        for (int m = 0; m < MF; m++)
            #pragma unroll
            for (int j = 0; j < 4; j++) acc[nt][m][j] = 0.f;

    #pragma unroll
    for (int kc = 0; kc < KC; kc++) {
        b16x8 a[MF];
        #pragma unroll
        for (int m = 0; m < MF; m++)
            a[m] = *(const b16x8*)&W16[(size_t)(m0 + m * 16 + lm) * (KC * 32) + kc * 32 + lk * 8];
        #pragma unroll
        for (int nt = 0; nt < 4; nt++) {
            const long px = wavepx + nt * 16 + lm;
            b16x8 bb;
            if (BSRC == 0) {
                bb = *(const b16x8*)&B16[(size_t)px * Brow + Boff + kc * 32 + lk * 8];
            } else {
                const int p = (int)(px & 65535), bat = (int)(px >> 16);
                #pragma unroll
                for (int j = 0; j < 8; j++) {
                    const int c = kc * 32 + lk * 8 + j;
                    float v = (c < Cin) ? Bf32[((size_t)(bat * Cin + c) << 16) + p] : 0.f;
                    bb[j] = (short)f2b(v);
                }
            }
            #pragma unroll
            for (int m = 0; m < MF; m++)
                acc[nt][m] = __builtin_amdgcn_mfma_f32_16x16x32_bf16(a[m], bb, acc[nt][m], 0, 0, 0);
        }
    }

    #pragma unroll
    for (int nt = 0; nt < 4; nt++) {
        const long px = wavepx + nt * 16 + lm;
        #pragma unroll
        for (int m = 0; m < MF; m++) {
            const int mrow = m * 16 + lk * 4;
            if (EPI == 0) {
                b16x4 o;
                #pragma unroll
                for (int j = 0; j < 4; j++) o[j] = (short)f2b(acc[nt][m][j]);
                *(b16x4*)&out16[(size_t)px * Crow + Coff + m0 + mrow] = o;
            } else if (EPI == 1) {
                const int p = (int)(px & 65535), bat = (int)(px >> 16);
                const int col = mrow + (mrow >= 48 ? 16 : 0);
                b16x4 r4 = *(const b16x4*)&res[(size_t)px * 128 + col];
                #pragma unroll
                for (int j = 0; j < 4; j++)
                    outf[((size_t)(bat * 96 + mrow + j) << 16) + p]
                        = acc[nt][m][j] + b2f((unsigned short)r4[j]);
            } else {
                const int p = (int)(px & 65535), bat = (int)(px >> 16);
                #pragma unroll
                for (int j = 0; j < 4; j++) {
                    const size_t adr = ((size_t)(bat * 96 + mrow + j) << 16) + p;
                    outf[adr] += acc[nt][m][j];
                }
            }
        }
    }
}

// ---------------------------------------------------------------------------
// Depthwise 3x3 (pad=1) on bf16 NHWC [px][C]. Thread = (px, 8-channel group).
// GATED: out = gelu_exact(gate[px][c]) * acc.
// ---------------------------------------------------------------------------
template<int GATED>
__global__ __launch_bounds__(256) void dwnhwc_k(
    const unsigned short* __restrict__ in, unsigned short* __restrict__ out,
    const float* __restrict__ wsrc, int wOff, int C,
    const unsigned short* __restrict__ gate)
{
    const int ng = C >> 3;
    const long idx = (long)blockIdx.x * 256 + threadIdx.x;
    const int g = (int)(idx % ng);
    const long px = idx / ng;
    const int p = (int)(px & 65535);
    const int y = p >> 8, x = p & 255;
    const int c0 = g * 8;

    float wreg[72];
    {
        const float4* w4 = (const float4*)(wsrc + (size_t)(wOff + c0) * 9);
        #pragma unroll
        for (int i = 0; i < 18; i++) {
            float4 t = w4[i];
            wreg[i * 4 + 0] = t.x; wreg[i * 4 + 1] = t.y;
            wreg[i * 4 + 2] = t.z; wreg[i * 4 + 3] = t.w;
        }
    }

    float acc[8];
    #pragma unroll
    for (int j = 0; j < 8; j++) acc[j] = 0.f;

    #pragma unroll
    for (int dy = -1; dy <= 1; dy++) {
        const int yy = y + dy;
        if ((unsigned)yy >= 256u) continue;
        #pragma unroll
        for (int dx = -1; dx <= 1; dx++) {
            const int xx = x + dx;
            if ((unsigned)xx >= 256u) continue;
            const int tap = (dy + 1) * 3 + (dx + 1);
            b16x8 v = *(const b16x8*)&in[(px + dy * 256 + dx) * C + c0];
            #pragma unroll
            for (int j = 0; j < 8; j++)
                acc[j] = fmaf(wreg[j * 9 + tap], b2f((unsigned short)v[j]), acc[j]);
        }
    }

    b16x8 o;
    if (GATED) {
        b16x8 gv = *(const b16x8*)&gate[px * C + c0];
        #pragma unroll
        for (int j = 0; j < 8; j++) {
            float gf = b2f((unsigned short)gv[j]);
            float ge = 0.5f * gf * (1.f + erff(gf * 0.70710678118654752440f));
            o[j] = (short)f2b(ge * acc[j]);
        }
    } else {
        #pragma unroll
        for (int j = 0; j < 8; j++) o[j] = (short)f2b(acc[j]);
    }
    *(b16x8*)&out[px * C + c0] = o;
}

// ---------------------------------------------------------------------------
// Attention stage A: partial q.k dots + sq-norms from NHWC Q tensors.
// a=0: q from Q2, k from Q1 (attn1); a=1: q from Q1, k from Q2.
// part[((a*16+bh)*32 + chunk)*48 + {dot[36], nq[6], nk[6]}]
// ---------------------------------------------------------------------------
__global__ __launch_bounds__(256) void attnA_k(
    const unsigned short* __restrict__ Q1, const unsigned short* __restrict__ Q2,
    float* __restrict__ part)
{
    const int tid = threadIdx.x;
    const int chunk = blockIdx.x, bh = blockIdx.y, a = blockIdx.z;
    const int b = bh >> 3, h = bh & 7;
    const unsigned* Qq = (const unsigned*)(a ? Q1 : Q2);
    const unsigned* Qk = (const unsigned*)(a ? Q2 : Q1);
    const int qw = 3 * h;        // uint offset of q within 72-uint row
    const int kw = 24 + 3 * h;   // uint offset of k

    float dot[36], nq[6], nk[6];
    #pragma unroll
    for (int i = 0; i < 36; i++) dot[i] = 0.f;
    #pragma unroll
    for (int i = 0; i < 6; i++) { nq[i] = 0.f; nk[i] = 0.f; }

    #pragma unroll 1
    for (int r = 0; r < 8; r++) {
        const long px = (long)b * 65536 + chunk * 2048 + r * 256 + tid;
        const size_t row = (size_t)px * 72;
        float q[6], k[6];
        #pragma unroll
        for (int i = 0; i < 3; i++) {
            union { unsigned u; float f; } lo, hi;
            unsigned uq = Qq[row + qw + i];
            lo.u = uq << 16; hi.u = uq & 0xFFFF0000u;
            q[2 * i] = lo.f; q[2 * i + 1] = hi.f;
            unsigned uk = Qk[row + kw + i];
            lo.u = uk << 16; hi.u = uk & 0xFFFF0000u;
            k[2 * i] = lo.f; k[2 * i + 1] = hi.f;
        }
        #pragma unroll
        for (int c = 0; c < 6; c++) nq[c] = fmaf(q[c], q[c], nq[c]);
        #pragma unroll
        for (int d = 0; d < 6; d++) nk[d] = fmaf(k[d], k[d], nk[d]);
        #pragma unroll
        for (int c = 0; c < 6; c++)
            #pragma unroll
            for (int d = 0; d < 6; d++) dot[c * 6 + d] = fmaf(q[c], k[d], dot[c * 6 + d]);
    }

    __shared__ float red[4][48];
    const int lane = tid & 63, wid = tid >> 6;
    #pragma unroll
    for (int i = 0; i < 48; i++) {
        float v = (i < 36) ? dot[i] : (i < 42 ? nq[i - 36] : nk[i - 42]);
        v = wave_reduce_sum(v);
        if (!lane) red[wid][i] = v;
    }
    __syncthreads();
    if (tid < 48)
        part[((size_t)((a * 16 + bh) * 32 + chunk)) * 48 + tid]
            = red[0][tid] + red[1][tid] + red[2][tid] + red[3][tid];
}

// Stage B: reduce partials, normalize, temperature, softmax -> ATT[1152].
__global__ void attnB_k(const float* __restrict__ part,
                        const float* __restrict__ t1, const float* __restrict__ t2,
                        float* __restrict__ att)
{
    const int abh = blockIdx.x, tid = threadIdx.x;
    const int a = abh >> 4, b = (abh >> 3) & 1, h = abh & 7;
    __shared__ float s[48];
    if (tid < 48) {
        float v = 0.f;
        for (int ch = 0; ch < 32; ch++) v += part[((size_t)abh * 32 + ch) * 48 + tid];
        s[tid] = v;
    }
    __syncthreads();
    if (tid < 6) {
        const int c = tid;
        const float tv = a ? t2[h] : t1[h];
        const float qn = fmaxf(sqrtf(s[36 + c]), 1e-12f);
        float raw[6];
        #pragma unroll
        for (int d = 0; d < 6; d++)
            raw[d] = tv * s[c * 6 + d] / (qn * fmaxf(sqrtf(s[42 + d]), 1e-12f));
        float m = raw[0];
        #pragma unroll
        for (int d = 1; d < 6; d++) m = fmaxf(m, raw[d]);
        float e[6], sum = 0.f;
        #pragma unroll
        for (int d = 0; d < 6; d++) { e[d] = expf(raw[d] - m); sum += e[d]; }
        const float inv = 1.f / sum;
        #pragma unroll
        for (int d = 0; d < 6; d++)
            att[((size_t)(a * 2 + b) * 8 + h) * 36 + c * 6 + d] = e[d] * inv;
    }
}

// ---------------------------------------------------------------------------
// Fused: S = softmax(att) @ V (per px, in regs) -> LDS; then MFMA mid conv;
// D16p[px][boff + 0..47] = x + mid @ S ; zero-pad cols boff+48..63.
// ---------------------------------------------------------------------------
__global__ __launch_bounds__(256) void mid_k(
    const unsigned short* __restrict__ Qv, const float* __restrict__ att,
    const float* __restrict__ x, const unsigned short* __restrict__ W16,
    unsigned short* __restrict__ D16p, int boff)
{
    __shared__ float atts[288];
    __shared__ unsigned short S[256][72];
    const int tid = threadIdx.x;
    const long px = (long)blockIdx.x * 256 + tid;
    const int bat = (int)(px >> 16);

    for (int i = tid; i < 288; i += 256) atts[i] = att[bat * 288 + i];

    float v[48];
    {
        const unsigned short* vp = Qv + (size_t)px * 144 + 96;
        #pragma unroll
        for (int i = 0; i < 6; i++) {
            b16x8 t = *(const b16x8*)&vp[i * 8];
            #pragma unroll
            for (int j = 0; j < 8; j++) v[i * 8 + j] = b2f((unsigned short)t[j]);
        }
    }
    __syncthreads();

    #pragma unroll
    for (int h = 0; h < 8; h++) {
        unsigned short sh[6];
        #pragma unroll
        for (int c = 0; c < 6; c++) {
            float s = 0.f;
            #pragma unroll
            for (int d = 0; d < 6; d++) s = fmaf(atts[h * 36 + c * 6 + d], v[h * 6 + d], s);
            sh[c] = f2b(s);
        }
        #pragma unroll
        for (int i = 0; i < 3; i++) {
            unsigned packed = (unsigned)sh[2 * i] | ((unsigned)sh[2 * i + 1] << 16);
            *(unsigned*)&S[tid][h * 6 + 2 * i] = packed;
        }
    }
    #pragma unroll
    for (int i = 0; i < 8; i++) *(unsigned*)&S[tid][48 + 2 * i] = 0u;
    __syncthreads();

    const int lane = tid & 63, w = tid >> 6;
    const int lm = lane & 15, lk = lane >> 4;
    f32x4 acc[4][3];
    #pragma unroll
    for (int nt = 0; nt < 4; nt++)
        #pragma unroll
        for (int m = 0; m < 3; m++)
            #pragma unroll
            for (int j = 0; j < 4; j++) acc[nt][m][j] = 0.f;

    #pragma unroll
    for (int kc = 0; kc < 2; kc++) {
        b16x8 a[3];
        #pragma unroll
        for (int m = 0; m < 3; m++)
            a[m] = *(const b16x8*)&W16[(size_t)(m * 16 + lm) * 64 + kc * 32 + lk * 8];
        #pragma unroll
        for (int nt = 0; nt < 4; nt++) {
            b16x8 bb = *(const b16x8*)&S[w * 64 + nt * 16 + lm][kc * 32 + lk * 8];
            #pragma unroll
            for (int m = 0; m < 3; m++)
                acc[nt][m] = __builtin_amdgcn_mfma_f32_16x16x32_bf16(a[m], bb, acc[nt][m], 0, 0, 0);
        }
    }

    #pragma unroll
    for (int nt = 0; nt < 4; nt++) {
        const long px2 = (long)blockIdx.x * 256 + w * 64 + nt * 16 + lm;
        const int p2 = (int)(px2 & 65535);
        #pragma unroll
        for (int m = 0; m < 3; m++) {
            const int row = m * 16 + lk * 4;
            b16x4 o;
            #pragma unroll
            for (int j = 0; j < 4; j++) {
                float xv = x[((size_t)(bat * 48 + row + j) << 16) + p2];
                o[j] = (short)f2b(acc[nt][m][j] + xv);
            }
            *(b16x4*)&D16p[(size_t)px2 * 128 + boff + row] = o;
        }
        b16x4 z; z[0] = 0; z[1] = 0; z[2] = 0; z[3] = 0;
        *(b16x4*)&D16p[(size_t)px2 * 128 + boff + 48 + lk * 4] = z;
    }
}

extern "C" void kernel_launch(void* const* d_in, const int* in_sizes, int n_in,
                              void* d_out, int out_size, void* d_ws, size_t ws_size,
                              hipStream_t stream) {
    const float* x1      = (const float*)d_in[0];
    const float* x2      = (const float*)d_in[1];
    const float* t1      = (const float*)d_in[2];
    const float* t2      = (const float*)d_in[3];
    const float* qkv1_w  = (const float*)d_in[4];
    const float* qkv1_dw = (const float*)d_in[5];
    const float* qkv2_w  = (const float*)d_in[6];
    const float* qkv2_dw = (const float*)d_in[7];
    const float* mid1_w  = (const float*)d_in[8];
    const float* mid2_w  = (const float*)d_in[9];
    const float* pE_w    = (const float*)d_in[10];
    const float* pE_dw   = (const float*)d_in[11];
    const float* pE1_w   = (const float*)d_in[12];
    const float* pE1_dw  = (const float*)d_in[13];
    const float* pE2_w   = (const float*)d_in[14];
    const float* pE2_dw  = (const float*)d_in[15];
    const float* po1_w   = (const float*)d_in[16];
    const float* po2_w   = (const float*)d_in[17];
    float* dout = (float*)d_out;
    char* ws = (char*)d_ws;

    // workspace layout (bytes); peak ~185 MB
    unsigned short* D16p  = (unsigned short*)(ws + 0);            // [131072][128]
    unsigned short* QKVc1 = (unsigned short*)(ws + 33554432);     // [131072][144]
    unsigned short* QKVc2 = (unsigned short*)(ws + 71303168);
    unsigned short* Q1    = (unsigned short*)(ws + 109051904);
    unsigned short* Q2    = (unsigned short*)(ws + 146800640);
    unsigned short* Gb    = (unsigned short*)(ws + 33554432);     // phase5 reuse
    unsigned short* G2b   = (unsigned short*)(ws + 83886080);
    unsigned short* Hb    = (unsigned short*)(ws + 134217728);
    unsigned short* Xgb   = (unsigned short*)(ws + 33554432);
    float*          PART  = (float*)(ws + 184549376);             // 49152 fl
    float*          ATT   = (float*)(ws + 184745984);             // 1152 fl
    unsigned short* W16   = (unsigned short*)(ws + 184750592);    // 135168 el
    unsigned short* Wq1  = W16 + 0;
    unsigned short* Wq2  = W16 + 9216;
    unsigned short* Wm1  = W16 + 18432;
    unsigned short* Wm2  = W16 + 21504;
    unsigned short* WpE  = W16 + 24576;
    unsigned short* Wp1  = W16 + 73728;
    unsigned short* Wp2  = W16 + 86016;
    unsigned short* Wo1  = W16 + 98304;
    unsigned short* Wo2  = W16 + 116736;

    const dim3 blk(256);

    wprep_k<<<dim3(528), blk, 0, stream>>>(
        qkv1_w, qkv2_w, mid1_w, mid2_w, pE_w, pE1_w, pE2_w, po1_w, po2_w, W16);

    // phase 1: qkv conv (fp32 NCHW input direct) + dw3x3
    gemm_k<144,2,1,0><<<dim3(512,1), blk, 0, stream>>>(
        nullptr, 0, 0, x1, 48, Wq1, QKVc1, 144, 0, nullptr, nullptr);
    gemm_k<144,2,1,0><<<dim3(512,1), blk, 0, stream>>>(
        nullptr, 0, 0, x2, 48, Wq2, QKVc2, 144, 0, nullptr, nullptr);
    dwnhwc_k<0><<<dim3(9216), blk, 0, stream>>>(QKVc1, Q1, qkv1_dw, 0, 144, nullptr);
    dwnhwc_k<0><<<dim3(9216), blk, 0, stream>>>(QKVc2, Q2, qkv2_dw, 0, 144, nullptr);

    // phase 2: fused norms+dots, softmax
    attnA_k<<<dim3(32,16,2), blk, 0, stream>>>(Q1, Q2, PART);
    attnB_k<<<dim3(32), dim3(64), 0, stream>>>(PART, t1, t2, ATT);

    // phase 3+4: attn-out + mid conv + residual -> D16p (stage-1, padded NHWC)
    mid_k<<<dim3(512), blk, 0, stream>>>(Q1, ATT,       x1, Wm1, D16p, 0);
    mid_k<<<dim3(512), blk, 0, stream>>>(Q2, ATT + 576, x2, Wm2, D16p, 64);

    // phase 5: gated FFN tail, per branch
    for (int br = 0; br < 2; br++) {
        gemm_k<96,4,0,0><<<dim3(512,2), blk, 0, stream>>>(
            D16p, 128, 0, nullptr, 0, WpE + (size_t)br * 192 * 128, Gb, 192, 0,
            nullptr, nullptr);
        dwnhwc_k<0><<<dim3(12288), blk, 0, stream>>>(Gb, G2b, pE_dw, br * 192, 192, nullptr);
        gemm_k<96,2,0,0><<<dim3(512,2), blk, 0, stream>>>(
            D16p, 128, br * 64, nullptr, 0, (br ? Wp2 : Wp1), Hb, 192, 0,
            nullptr, nullptr);
        dwnhwc_k<1><<<dim3(12288), blk, 0, stream>>>(
            Hb, Xgb, (br ? pE2_dw : pE1_dw), 0, 192, G2b);
        if (br == 0)
            gemm_k<96,6,0,1><<<dim3(512,1), blk, 0, stream>>>(
                Xgb, 192, 0, nullptr, 0, Wo1, nullptr, 0, 0, dout, D16p);
        else
            gemm_k<96,6,0,2><<<dim3(512,1), blk, 0, stream>>>(
                Xgb, 192, 0, nullptr, 0, Wo2, nullptr, 0, 0, dout, nullptr);
    }
}

// Round 4
// 489.878 us; speedup vs baseline: 5.2128x; 1.5688x over previous
//
#include <hip/hip_runtime.h>
#include <math.h>

#define HW_ 65536

typedef __attribute__((ext_vector_type(8))) short b16x8;
typedef __attribute__((ext_vector_type(4))) short b16x4;
typedef __attribute__((ext_vector_type(4))) float f32x4;

__device__ __forceinline__ unsigned short f2b(float f) {
    union { float f; unsigned u; } v; v.f = f;
    unsigned r = v.u + 0x7fffu + ((v.u >> 16) & 1u);
    return (unsigned short)(r >> 16);
}
__device__ __forceinline__ float b2f(unsigned short h) {
    union { unsigned u; float f; } v; v.u = ((unsigned)h) << 16; return v.f;
}

__device__ __forceinline__ float wave_reduce_sum(float v) {
    #pragma unroll
    for (int off = 32; off; off >>= 1) v += __shfl_down(v, off, 64);
    return v;
}

// ---------------------------------------------------------------------------
// Weight prep.
// bf16 section (row-major [M][Kpad]):
//  Wq1@0 [144][64] | Wq2@9216 | Wm1@18432 [48][64] | Wm2@21504
//  WGH1@24576 [384][128] | WGH2@73728  (rows 0..191 pE slice w/ D16p col map;
//      rows 192..383 pE1/pE2 mapped into cols br*64..br*64+47)
//  Wo1@122880 [96][192] | Wo2@141312 ; end 159744
// fp32 dw-transpose section dwt[t*C + c] = src[c*9+t]:
//  q1dw@0 [9][144] | q2dw@1296 | pEdw@2592 [9][384] | p1dw@6048 [9][192]
//  | p2dw@7776 ; end 9504
// ---------------------------------------------------------------------------
__global__ __launch_bounds__(256) void wprep_k(
    const float* __restrict__ q1w, const float* __restrict__ q2w,
    const float* __restrict__ m1w, const float* __restrict__ m2w,
    const float* __restrict__ pEw, const float* __restrict__ p1w,
    const float* __restrict__ p2w, const float* __restrict__ o1w,
    const float* __restrict__ o2w,
    const float* __restrict__ q1dw, const float* __restrict__ q2dw,
    const float* __restrict__ pEdw, const float* __restrict__ p1dw,
    const float* __restrict__ p2dw,
    unsigned short* __restrict__ wt, float* __restrict__ dwt)
{
    const int idx = blockIdx.x * 256 + threadIdx.x;
    if (idx < 159744) {
        const int base[8] = {0,9216,18432,21504,24576,73728,122880,141312};
        int s = 0;
        #pragma unroll
        for (int i = 1; i < 8; i++) if (idx >= base[i]) s = i;
        const int local = idx - base[s];
        float v = 0.f;
        if (s < 4) {
            const int m = local >> 6, k = local & 63;
            const float* src = (s == 0) ? q1w : (s == 1) ? q2w : (s == 2) ? m1w : m2w;
            if (k < 48) v = src[m * 48 + k];
        } else if (s < 6) {
            const int br = s - 4;
            const int m = local >> 7, k = local & 127;
            if (m < 192) {
                int kk = (k < 48) ? k : ((k >= 64 && k < 112) ? k - 16 : -1);
                if (kk >= 0) v = pEw[(size_t)(br * 192 + m) * 96 + kk];
            } else {
                const float* p12 = br ? p2w : p1w;
                const int lo = br * 64, m2 = m - 192;
                if (k >= lo && k < lo + 48) v = p12[m2 * 48 + (k - lo)];
            }
        } else {
            const int m = local / 192, k = local % 192;
            v = ((s == 6) ? o1w : o2w)[m * 192 + k];
        }
        wt[idx] = f2b(v);
    } else if (idx < 159744 + 9504) {
        const int d = idx - 159744;
        const int dbase[5] = {0,1296,2592,6048,7776};
        const int Cs[5] = {144,144,384,192,192};
        int s = 0;
        #pragma unroll
        for (int i = 1; i < 5; i++) if (d >= dbase[i]) s = i;
        const int local = d - dbase[s], C = Cs[s];
        const int t = local / C, c = local % C;
        const float* src = (s == 0) ? q1dw : (s == 1) ? q2dw : (s == 2) ? pEdw
                         : (s == 3) ? p1dw : p2dw;
        dwt[d] = src[c * 9 + t];
    }
}

// ---------------------------------------------------------------------------
// MFMA GEMM (unchanged from round 3): D[m, px] = W[m,k] * X[k,px].
// ---------------------------------------------------------------------------
template<int BM, int KC, int BSRC, int EPI>
__global__ __launch_bounds__(256) void gemm_k(
    const unsigned short* __restrict__ B16, int Brow, int Boff,
    const float* __restrict__ Bf32, int Cin,
    const unsigned short* __restrict__ W16,
    unsigned short* __restrict__ out16, int Crow, int Coff,
    float* __restrict__ outf, const unsigned short* __restrict__ res)
{
    constexpr int MF = BM / 16;
    const int tid = threadIdx.x;
    const int lane = tid & 63, w = tid >> 6;
    const int lm = lane & 15, lk = lane >> 4;
    const int m0 = blockIdx.y * BM;
    const long wavepx = (long)blockIdx.x * 256 + w * 64;

    f32x4 acc[4][MF];
    #pragma unroll
    for (int nt = 0; nt < 4; nt++)
        #pragma unroll
        for (int m = 0; m < MF; m++)
            #pragma unroll
            for (int j = 0; j < 4; j++) acc[nt][m][j] = 0.f;

    #pragma unroll
    for (int kc = 0; kc < KC; kc++) {
        b16x8 a[MF];
        #pragma unroll
        for (int m = 0; m < MF; m++)
            a[m] = *(const b16x8*)&W16[(size_t)(m0 + m * 16 + lm) * (KC * 32) + kc * 32 + lk * 8];
        #pragma unroll
        for (int nt = 0; nt < 4; nt++) {
            const long px = wavepx + nt * 16 + lm;
            b16x8 bb;
            if (BSRC == 0) {
                bb = *(const b16x8*)&B16[(size_t)px * Brow + Boff + kc * 32 + lk * 8];
            } else {
                const int p = (int)(px & 65535), bat = (int)(px >> 16);
                #pragma unroll
                for (int j = 0; j < 8; j++) {
                    const int c = kc * 32 + lk * 8 + j;
                    float v = (c < Cin) ? Bf32[((size_t)(bat * Cin + c) << 16) + p] : 0.f;
                    bb[j] = (short)f2b(v);
                }
            }
            #pragma unroll
            for (int m = 0; m < MF; m++)
                acc[nt][m] = __builtin_amdgcn_mfma_f32_16x16x32_bf16(a[m], bb, acc[nt][m], 0, 0, 0);
        }
    }

    #pragma unroll
    for (int nt = 0; nt < 4; nt++) {
        const long px = wavepx + nt * 16 + lm;
        #pragma unroll
        for (int m = 0; m < MF; m++) {
            const int mrow = m * 16 + lk * 4;
            if (EPI == 0) {
                b16x4 o;
                #pragma unroll
                for (int j = 0; j < 4; j++) o[j] = (short)f2b(acc[nt][m][j]);
                *(b16x4*)&out16[(size_t)px * Crow + Coff + m0 + mrow] = o;
            } else if (EPI == 1) {
                const int p = (int)(px & 65535), bat = (int)(px >> 16);
                const int col = mrow + (mrow >= 48 ? 16 : 0);
                b16x4 r4 = *(const b16x4*)&res[(size_t)px * 128 + col];
                #pragma unroll
                for (int j = 0; j < 4; j++)
                    outf[((size_t)(bat * 96 + mrow + j) << 16) + p]
                        = acc[nt][m][j] + b2f((unsigned short)r4[j]);
            } else {
                const int p = (int)(px & 65535), bat = (int)(px >> 16);
                #pragma unroll
                for (int j = 0; j < 4; j++) {
                    const size_t adr = ((size_t)(bat * 96 + mrow + j) << 16) + p;
                    outf[adr] += acc[nt][m][j];
                }
            }
        }
    }
}

// ---------------------------------------------------------------------------
// Depthwise 3x3 core: 4 horizontal px (x0..x0+3) x 8 channels.
// 18 halo loads serve all 36 (px,tap) pairs. Weights fp32 [9][wstr] slices.
// ---------------------------------------------------------------------------
__device__ __forceinline__ void dw_acc8(
    float acc[4][8], const unsigned short* __restrict__ ip, int cstr,
    const float* __restrict__ wt, int wstr, int y, int x0)
{
    #pragma unroll
    for (int dy = -1; dy <= 1; dy++) {
        const int yy = y + dy;
        if ((unsigned)yy >= 256u) continue;
        float w[3][8];
        #pragma unroll
        for (int t = 0; t < 3; t++) {
            const float* wp = wt + (size_t)((dy + 1) * 3 + t) * wstr;
            const float4 a = *(const float4*)wp;
            const float4 b = *(const float4*)(wp + 4);
            w[t][0] = a.x; w[t][1] = a.y; w[t][2] = a.z; w[t][3] = a.w;
            w[t][4] = b.x; w[t][5] = b.y; w[t][6] = b.z; w[t][7] = b.w;
        }
        #pragma unroll
        for (int c = 0; c < 6; c++) {
            const int xx = x0 - 1 + c;
            b16x8 v;
            if ((unsigned)xx < 256u) {
                v = *(const b16x8*)(ip + (long)(dy * 256 + (c - 1)) * cstr);
            } else {
                #pragma unroll
                for (int k = 0; k < 8; k++) v[k] = 0;
            }
            float f[8];
            #pragma unroll
            for (int k = 0; k < 8; k++) f[k] = b2f((unsigned short)v[k]);
            const int ilo = (c - 2 < 0) ? 0 : c - 2;
            const int ihi = (c < 3) ? c : 3;
            #pragma unroll
            for (int i = ilo; i <= ihi; i++)
                #pragma unroll
                for (int j = 0; j < 8; j++)
                    acc[i][j] = fmaf(w[c - i][j], f[j], acc[i][j]);
        }
    }
}

// phase-1 depthwise: C=144, both branches via blockIdx.z. 2304 blocks/branch.
__global__ __launch_bounds__(256) void dw144_k(
    const unsigned short* __restrict__ in1, unsigned short* __restrict__ out1,
    const unsigned short* __restrict__ in2, unsigned short* __restrict__ out2,
    const float* __restrict__ dwt)
{
    const int z = blockIdx.z;
    const unsigned short* in = z ? in2 : in1;
    unsigned short* out = z ? out2 : out1;
    const float* wt = dwt + z * 1296;
    const int idx = blockIdx.x * 256 + threadIdx.x;   // < 589824
    const int g = idx % 18;
    const int s = idx / 18;
    const int bat = s >> 14, sp = s & 16383;
    const int p0 = sp * 4, y = p0 >> 8, x0 = p0 & 255;
    const size_t base = ((size_t)(bat << 16) + p0) * 144 + g * 8;

    float acc[4][8];
    #pragma unroll
    for (int i = 0; i < 4; i++)
        #pragma unroll
        for (int j = 0; j < 8; j++) acc[i][j] = 0.f;
    dw_acc8(acc, in + base, 144, wt + g * 8, 144, y, x0);
    #pragma unroll
    for (int i = 0; i < 4; i++) {
        b16x8 o;
        #pragma unroll
        for (int j = 0; j < 8; j++) o[j] = (short)f2b(acc[i][j]);
        *(b16x8*)&out[base + (size_t)i * 144] = o;
    }
}

// tail fused: Xg = gelu(dw(GH[:,0:192])) * dw(GH[:,192:384]). 3072 blocks.
__global__ __launch_bounds__(256) void dwtail_k(
    const unsigned short* __restrict__ GH, unsigned short* __restrict__ Xg,
    const float* __restrict__ dwtG, const float* __restrict__ dwtH)
{
    const int idx = blockIdx.x * 256 + threadIdx.x;   // < 786432
    const int g = idx % 24;
    const int s = idx / 24;
    const int bat = s >> 14, sp = s & 16383;
    const int p0 = sp * 4, y = p0 >> 8, x0 = p0 & 255;
    const size_t rb = ((size_t)(bat << 16) + p0) * 384;

    float aG[4][8], aH[4][8];
    #pragma unroll
    for (int i = 0; i < 4; i++)
        #pragma unroll
        for (int j = 0; j < 8; j++) { aG[i][j] = 0.f; aH[i][j] = 0.f; }
    dw_acc8(aG, GH + rb + g * 8, 384, dwtG + g * 8, 384, y, x0);
    dw_acc8(aH, GH + rb + 192 + g * 8, 384, dwtH + g * 8, 192, y, x0);

    #pragma unroll
    for (int i = 0; i < 4; i++) {
        b16x8 o;
        #pragma unroll
        for (int j = 0; j < 8; j++) {
            const float gf = aG[i][j];
            const float ge = 0.5f * gf * (1.f + erff(gf * 0.70710678118654752440f));
            o[j] = (short)f2b(ge * aH[i][j]);
        }
        *(b16x8*)&Xg[((size_t)(bat << 16) + p0 + i) * 192 + g * 8] = o;
    }
}

// ---------------------------------------------------------------------------
// Attention stage A (unchanged): partial q.k dots + sq-norms, NHWC bf16.
// ---------------------------------------------------------------------------
__global__ __launch_bounds__(256) void attnA_k(
    const unsigned short* __restrict__ Q1, const unsigned short* __restrict__ Q2,
    float* __restrict__ part)
{
    const int tid = threadIdx.x;
    const int chunk = blockIdx.x, bh = blockIdx.y, a = blockIdx.z;
    const int b = bh >> 3, h = bh & 7;
    const unsigned* Qq = (const unsigned*)(a ? Q1 : Q2);
    const unsigned* Qk = (const unsigned*)(a ? Q2 : Q1);
    const int qw = 3 * h;
    const int kw = 24 + 3 * h;

    float dot[36], nq[6], nk[6];
    #pragma unroll
    for (int i = 0; i < 36; i++) dot[i] = 0.f;
    #pragma unroll
    for (int i = 0; i < 6; i++) { nq[i] = 0.f; nk[i] = 0.f; }

    #pragma unroll 1
    for (int r = 0; r < 8; r++) {
        const long px = (long)b * 65536 + chunk * 2048 + r * 256 + tid;
        const size_t row = (size_t)px * 72;
        float q[6], k[6];
        #pragma unroll
        for (int i = 0; i < 3; i++) {
            union { unsigned u; float f; } lo, hi;
            unsigned uq = Qq[row + qw + i];
            lo.u = uq << 16; hi.u = uq & 0xFFFF0000u;
            q[2 * i] = lo.f; q[2 * i + 1] = hi.f;
            unsigned uk = Qk[row + kw + i];
            lo.u = uk << 16; hi.u = uk & 0xFFFF0000u;
            k[2 * i] = lo.f; k[2 * i + 1] = hi.f;
        }
        #pragma unroll
        for (int c = 0; c < 6; c++) nq[c] = fmaf(q[c], q[c], nq[c]);
        #pragma unroll
        for (int d = 0; d < 6; d++) nk[d] = fmaf(k[d], k[d], nk[d]);
        #pragma unroll
        for (int c = 0; c < 6; c++)
            #pragma unroll
            for (int d = 0; d < 6; d++) dot[c * 6 + d] = fmaf(q[c], k[d], dot[c * 6 + d]);
    }

    __shared__ float red[4][48];
    const int lane = tid & 63, wid = tid >> 6;
    #pragma unroll
    for (int i = 0; i < 48; i++) {
        float v = (i < 36) ? dot[i] : (i < 42 ? nq[i - 36] : nk[i - 42]);
        v = wave_reduce_sum(v);
        if (!lane) red[wid][i] = v;
    }
    __syncthreads();
    if (tid < 48)
        part[((size_t)((a * 16 + bh) * 32 + chunk)) * 48 + tid]
            = red[0][tid] + red[1][tid] + red[2][tid] + red[3][tid];
}

__global__ void attnB_k(const float* __restrict__ part,
                        const float* __restrict__ t1, const float* __restrict__ t2,
                        float* __restrict__ att)
{
    const int abh = blockIdx.x, tid = threadIdx.x;
    const int a = abh >> 4, b = (abh >> 3) & 1, h = abh & 7;
    __shared__ float s[48];
    if (tid < 48) {
        float v = 0.f;
        for (int ch = 0; ch < 32; ch++) v += part[((size_t)abh * 32 + ch) * 48 + tid];
        s[tid] = v;
    }
    __syncthreads();
    if (tid < 6) {
        const int c = tid;
        const float tv = a ? t2[h] : t1[h];
        const float qn = fmaxf(sqrtf(s[36 + c]), 1e-12f);
        float raw[6];
        #pragma unroll
        for (int d = 0; d < 6; d++)
            raw[d] = tv * s[c * 6 + d] / (qn * fmaxf(sqrtf(s[42 + d]), 1e-12f));
        float m = raw[0];
        #pragma unroll
        for (int d = 1; d < 6; d++) m = fmaxf(m, raw[d]);
        float e[6], sum = 0.f;
        #pragma unroll
        for (int d = 0; d < 6; d++) { e[d] = expf(raw[d] - m); sum += e[d]; }
        const float inv = 1.f / sum;
        #pragma unroll
        for (int d = 0; d < 6; d++)
            att[((size_t)(a * 2 + b) * 8 + h) * 36 + c * 6 + d] = e[d] * inv;
    }
}

// ---------------------------------------------------------------------------
// Fused attn-out + mid conv + residual; both branches via blockIdx.y.
// ---------------------------------------------------------------------------
__global__ __launch_bounds__(256) void mid_k(
    const unsigned short* __restrict__ Q1, const unsigned short* __restrict__ Q2,
    const float* __restrict__ att,
    const float* __restrict__ x1, const float* __restrict__ x2,
    const unsigned short* __restrict__ Wm, unsigned short* __restrict__ D16p)
{
    const int br = blockIdx.y;
    const unsigned short* Qv = br ? Q2 : Q1;
    const float* x = br ? x2 : x1;
    const unsigned short* W16 = Wm + br * 3072;
    const float* attb = att + br * 576;
    const int boff = br * 64;

    __shared__ float atts[288];
    __shared__ unsigned short S[256][72];
    const int tid = threadIdx.x;
    const long px = (long)blockIdx.x * 256 + tid;
    const int bat = (int)(px >> 16);

    for (int i = tid; i < 288; i += 256) atts[i] = attb[bat * 288 + i];

    float v[48];
    {
        const unsigned short* vp = Qv + (size_t)px * 144 + 96;
        #pragma unroll
        for (int i = 0; i < 6; i++) {
            b16x8 t = *(const b16x8*)&vp[i * 8];
            #pragma unroll
            for (int j = 0; j < 8; j++) v[i * 8 + j] = b2f((unsigned short)t[j]);
        }
    }
    __syncthreads();

    #pragma unroll
    for (int h = 0; h < 8; h++) {
        unsigned short sh[6];
        #pragma unroll
        for (int c = 0; c < 6; c++) {
            float s = 0.f;
            #pragma unroll
            for (int d = 0; d < 6; d++) s = fmaf(atts[h * 36 + c * 6 + d], v[h * 6 + d], s);
            sh[c] = f2b(s);
        }
        #pragma unroll
        for (int i = 0; i < 3; i++) {
            unsigned packed = (unsigned)sh[2 * i] | ((unsigned)sh[2 * i + 1] << 16);
            *(unsigned*)&S[tid][h * 6 + 2 * i] = packed;
        }
    }
    #pragma unroll
    for (int i = 0; i < 8; i++) *(unsigned*)&S[tid][48 + 2 * i] = 0u;
    __syncthreads();

    const int lane = tid & 63, w = tid >> 6;
    const int lm = lane & 15, lk = lane >> 4;
    f32x4 acc[4][3];
    #pragma unroll
    for (int nt = 0; nt < 4; nt++)
        #pragma unroll
        for (int m = 0; m < 3; m++)
            #pragma unroll
            for (int j = 0; j < 4; j++) acc[nt][m][j] = 0.f;

    #pragma unroll
    for (int kc = 0; kc < 2; kc++) {
        b16x8 a[3];
        #pragma unroll
        for (int m = 0; m < 3; m++)
            a[m] = *(const b16x8*)&W16[(size_t)(m * 16 + lm) * 64 + kc * 32 + lk * 8];
        #pragma unroll
        for (int nt = 0; nt < 4; nt++) {
            b16x8 bb = *(const b16x8*)&S[w * 64 + nt * 16 + lm][kc * 32 + lk * 8];
            #pragma unroll
            for (int m = 0; m < 3; m++)
                acc[nt][m] = __builtin_amdgcn_mfma_f32_16x16x32_bf16(a[m], bb, acc[nt][m], 0, 0, 0);
        }
    }

    #pragma unroll
    for (int nt = 0; nt < 4; nt++) {
        const long px2 = (long)blockIdx.x * 256 + w * 64 + nt * 16 + lm;
        const int p2 = (int)(px2 & 65535);
        #pragma unroll
        for (int m = 0; m < 3; m++) {
            const int row = m * 16 + lk * 4;
            b16x4 o;
            #pragma unroll
            for (int j = 0; j < 4; j++) {
                float xv = x[((size_t)(bat * 48 + row + j) << 16) + p2];
                o[j] = (short)f2b(acc[nt][m][j] + xv);
            }
            *(b16x4*)&D16p[(size_t)px2 * 128 + boff + row] = o;
        }
        b16x4 z; z[0] = 0; z[1] = 0; z[2] = 0; z[3] = 0;
        *(b16x4*)&D16p[(size_t)px2 * 128 + boff + 48 + lk * 4] = z;
    }
}

extern "C" void kernel_launch(void* const* d_in, const int* in_sizes, int n_in,
                              void* d_out, int out_size, void* d_ws, size_t ws_size,
                              hipStream_t stream) {
    const float* x1      = (const float*)d_in[0];
    const float* x2      = (const float*)d_in[1];
    const float* t1      = (const float*)d_in[2];
    const float* t2      = (const float*)d_in[3];
    const float* qkv1_w  = (const float*)d_in[4];
    const float* qkv1_dw = (const float*)d_in[5];
    const float* qkv2_w  = (const float*)d_in[6];
    const float* qkv2_dw = (const float*)d_in[7];
    const float* mid1_w  = (const float*)d_in[8];
    const float* mid2_w  = (const float*)d_in[9];
    const float* pE_w    = (const float*)d_in[10];
    const float* pE_dw   = (const float*)d_in[11];
    const float* pE1_w   = (const float*)d_in[12];
    const float* pE1_dw  = (const float*)d_in[13];
    const float* pE2_w   = (const float*)d_in[14];
    const float* pE2_dw  = (const float*)d_in[15];
    const float* po1_w   = (const float*)d_in[16];
    const float* po2_w   = (const float*)d_in[17];
    float* dout = (float*)d_out;
    char* ws = (char*)d_ws;

    // workspace layout (bytes); peak ~185.1 MB
    unsigned short* D16p  = (unsigned short*)(ws + 0);            // [131072][128]
    unsigned short* QKVc1 = (unsigned short*)(ws + 33554432);     // [131072][144]
    unsigned short* QKVc2 = (unsigned short*)(ws + 71303168);
    unsigned short* Q1    = (unsigned short*)(ws + 109051904);
    unsigned short* Q2    = (unsigned short*)(ws + 146800640);
    unsigned short* GH    = (unsigned short*)(ws + 33554432);     // [131072][384] phase5
    unsigned short* Xg    = (unsigned short*)(ws + 134217728);    // [131072][192] phase5
    float*          PART  = (float*)(ws + 184549376);             // 49152 fl
    float*          ATT   = (float*)(ws + 184745984);             // 1152 fl
    unsigned short* W16   = (unsigned short*)(ws + 184750592);    // 159744 el
    float*          DWT   = (float*)(ws + 185070080);             // 9504 fl

    const dim3 blk(256);

    wprep_k<<<dim3(662), blk, 0, stream>>>(
        qkv1_w, qkv2_w, mid1_w, mid2_w, pE_w, pE1_w, pE2_w, po1_w, po2_w,
        qkv1_dw, qkv2_dw, pE_dw, pE1_dw, pE2_dw, W16, DWT);

    // phase 1: qkv conv (fp32 NCHW input) + depthwise
    gemm_k<144,2,1,0><<<dim3(512,1), blk, 0, stream>>>(
        nullptr, 0, 0, x1, 48, W16, QKVc1, 144, 0, nullptr, nullptr);
    gemm_k<144,2,1,0><<<dim3(512,1), blk, 0, stream>>>(
        nullptr, 0, 0, x2, 48, W16 + 9216, QKVc2, 144, 0, nullptr, nullptr);
    dw144_k<<<dim3(2304,1,2), blk, 0, stream>>>(QKVc1, Q1, QKVc2, Q2, DWT);

    // phase 2: fused norms+dots, softmax
    attnA_k<<<dim3(32,16,2), blk, 0, stream>>>(Q1, Q2, PART);
    attnB_k<<<dim3(32), dim3(64), 0, stream>>>(PART, t1, t2, ATT);

    // phase 3+4: attn-out + mid conv + residual -> D16p (both branches)
    mid_k<<<dim3(512,2), blk, 0, stream>>>(Q1, Q2, ATT, x1, x2, W16 + 18432, D16p);

    // phase 5: gated FFN tail per branch
    for (int br = 0; br < 2; br++) {
        gemm_k<96,4,0,0><<<dim3(512,4), blk, 0, stream>>>(
            D16p, 128, 0, nullptr, 0, W16 + 24576 + br * 49152, GH, 384, 0,
            nullptr, nullptr);
        dwtail_k<<<dim3(3072), blk, 0, stream>>>(
            GH, Xg, DWT + 2592 + br * 192, DWT + (br ? 7776 : 6048));
        if (br == 0)
            gemm_k<96,6,0,1><<<dim3(512,1), blk, 0, stream>>>(
                Xg, 192, 0, nullptr, 0, W16 + 122880, nullptr, 0, 0, dout, D16p);
        else
            gemm_k<96,6,0,2><<<dim3(512,1), blk, 0, stream>>>(
                Xg, 192, 0, nullptr, 0, W16 + 141312, nullptr, 0, 0, dout, nullptr);
    }
}